// Round 18
// baseline (391.374 us; speedup 1.0000x reference)
//
#include <hip/hip_runtime.h>
#include <hip/hip_bf16.h>
#include <limits.h>

// ---------------- problem constants ----------------
#define N_NODES 50000
#define N_EDGES 800000
#define TOT_E   (N_EDGES + N_NODES)   // with self loops
#define IN_F    38
#define HIDC    64
#define NH      4
#define F1      256                    // NH*HIDC
#define F2      128                    // OUT
#define NGRAPH  128
#define NEG_SLOPE 0.2f
#define EPS_A   1e-16f

typedef __hip_bfloat16 bf16;
typedef unsigned char fp8_t;           // OCP e4m3 raw byte
typedef __attribute__((ext_vector_type(8))) short short8;
typedef __attribute__((ext_vector_type(16))) float f32x16;
typedef __attribute__((ext_vector_type(2))) float f2;   // lowers to VOP3P v_pk_*_f32

// ---------------- ws layout ----------------
constexpr size_t al256(size_t x) { return (x + 255) & ~(size_t)255; }

// converted-params element offsets (f32 elements)
#define P_WL1   0
#define P_BL1   (P_WL1 + IN_F * F1)
#define P_WR1   (P_BL1 + F1)
#define P_BR1   (P_WR1 + IN_F * F1)
#define P_ATT1  (P_BR1 + F1)
#define P_BIAS1 (P_ATT1 + F1)
#define P_WL2   (P_BIAS1 + F1)
#define P_BL2   (P_WL2 + F1 * F2)
#define P_WR2   (P_BL2 + F2)
#define P_BR2   (P_WR2 + F1 * F2)
#define P_ATT2  (P_BR2 + F2)
#define P_BIAS2 (P_ATT2 + F2)
#define P_TOTAL (P_BIAS2 + F2)         // 86528 = 338*256

constexpr size_t OFF_PAR  = 256;
constexpr size_t OFF_XL1  = OFF_PAR + al256((size_t)P_TOTAL * 4);   // fp8 N*256; reused as h2
constexpr size_t OFF_XR1  = OFF_XL1 + al256((size_t)N_NODES * F1 * 2);
constexpr size_t OFF_H    = OFF_XR1 + al256((size_t)N_NODES * F1 * 2);
constexpr size_t OFF_XL2  = OFF_H   + al256((size_t)N_NODES * F1 * 2);  // fp8 N*128
constexpr size_t OFF_XR2  = OFF_XL2 + al256((size_t)N_NODES * F2 * 2);
// --- zero-init region (single memset): cnt | gs | ge | psum | done ---
constexpr size_t OFF_CNT  = OFF_XR2 + al256((size_t)N_NODES * F2 * 2);
constexpr size_t OFF_GS   = OFF_CNT + al256((size_t)N_NODES * 4);
constexpr size_t OFF_GE   = OFF_GS  + al256((size_t)NGRAPH * 4);
constexpr size_t OFF_PSUM = OFF_GE  + al256((size_t)NGRAPH * 4);
constexpr size_t OFF_DONE = OFF_PSUM+ al256((size_t)NGRAPH * F2 * 4);
constexpr size_t OFF_ZEND = OFF_DONE+ al256((size_t)NGRAPH * 4);
// --- rest ---
constexpr size_t OFF_OFFS = OFF_ZEND;                               // final (N+1)
constexpr size_t OFF_OFFSP= OFF_OFFS+ al256((size_t)(N_NODES + 1) * 4); // partial (N)
constexpr size_t OFF_CSR  = OFF_OFFSP+ al256((size_t)N_NODES * 4);
constexpr size_t OFF_WT1  = OFF_CSR + al256((size_t)TOT_E * 4);     // 512x64 bf16
constexpr size_t OFF_WT2  = OFF_WT1 + al256((size_t)512 * 64 * 2);  // 256x256 bf16
constexpr size_t OFF_BS   = OFF_WT2 + al256((size_t)256 * 256 * 2); // 49 block sums
constexpr size_t OFF_RANK = OFF_BS  + al256(64 * 4);                // per-edge rank
constexpr size_t OFF_H2   = OFF_XL1;  // xl1 dead after agg1
constexpr size_t OFF_XB   = OFF_H;    // xb dead before agg1 writes h

#define SCAN_BLKS 49   // ceil(50000/1024)
#define GBLK 1563      // ceil(50000/32)
#define SBL  831       // ceil(TOT_E/1024)
#define MEGA_SCANC 196 // scan_c blocks inside mega_k

// ---------------- helpers ----------------
__device__ __forceinline__ void unpack8bf2(uint4 q, f2* f) {
  unsigned v[4] = {q.x, q.y, q.z, q.w};
#pragma unroll
  for (int i = 0; i < 4; i++) {
    f2 t;
    t.x = __uint_as_float(v[i] << 16);
    t.y = __uint_as_float(v[i] & 0xffff0000u);
    f[i] = t;
  }
}

__device__ __forceinline__ void load8bf2(const bf16* __restrict__ p, f2* f) {
  unpack8bf2(*(const uint4*)p, f);
}

// 8 fp8 bytes -> 4 x f2 via HW v_cvt_pk_f32_fp8
__device__ __forceinline__ void unpack8fp8(uint2 q, f2* f) {
  f[0] = __builtin_amdgcn_cvt_pk_f32_fp8(q.x, false);
  f[1] = __builtin_amdgcn_cvt_pk_f32_fp8(q.x, true);
  f[2] = __builtin_amdgcn_cvt_pk_f32_fp8(q.y, false);
  f[3] = __builtin_amdgcn_cvt_pk_f32_fp8(q.y, true);
}

__device__ __forceinline__ fp8_t f32_to_fp8(float v) {
  return (fp8_t)(__builtin_amdgcn_cvt_pk_fp8_f32(v, v, 0, false) & 0xFF);
}

// leaky_relu(s) = 0.6*s + 0.4*|s|
__device__ __forceinline__ f2 lrelu2(f2 s) {
  f2 as;
  as.x = __uint_as_float(__float_as_uint(s.x) & 0x7fffffffu);
  as.y = __uint_as_float(__float_as_uint(s.y) & 0x7fffffffu);
  return 0.6f * s + 0.4f * as;
}

// wave-cooperative dtype sniff: 1 = inputs are f32, 0 = bf16.
__device__ __forceinline__ int detect_f32_wave(const void* __restrict__ x) {
  const unsigned short* u = (const unsigned short*)x;
  unsigned short b = u[threadIdx.x & 63];
  int e = (b >> 7) & 0xFF;
  unsigned long long m = __ballot(!((e == 0) || (e >= 96 && e <= 158)));
  return __popcll(m) > 8;
}

// ---------------- fused prep kernel (MLP-widened) ----------------
#define B_CVT  338
#define B_XP   1563    // 8 channels/thread
#define B_W1   128
#define B_W2   256
#define B_BND  196
#define B_CNT  831     // 4 edges/thread

struct PrepArgs {
  const void* x;
  const void* src[12];
  const int* ei;
  const int* batch;
};

__global__ __launch_bounds__(256) void prep_k(
    PrepArgs a, float* __restrict__ par, bf16* __restrict__ xb,
    bf16* __restrict__ wt1, bf16* __restrict__ wt2,
    int* __restrict__ gs, int* __restrict__ ge, int* __restrict__ cnt,
    int* __restrict__ rank) {
  int b = blockIdx.x;
  const int tid = threadIdx.x;

  if (b < B_CVT) {                       // ---- param convert -> f32 ----
    const int flag = detect_f32_wave(a.x);
    int idx = b * 256 + tid;
    const void* p; int base;
    if      (idx < P_BL1)  { p = a.src[0];  base = P_WL1; }
    else if (idx < P_WR1)  { p = a.src[1];  base = P_BL1; }
    else if (idx < P_BR1)  { p = a.src[2];  base = P_WR1; }
    else if (idx < P_ATT1) { p = a.src[3];  base = P_BR1; }
    else if (idx < P_BIAS1){ p = a.src[4];  base = P_ATT1; }
    else if (idx < P_WL2)  { p = a.src[5];  base = P_BIAS1; }
    else if (idx < P_BL2)  { p = a.src[6];  base = P_WL2; }
    else if (idx < P_WR2)  { p = a.src[7];  base = P_BL2; }
    else if (idx < P_BR2)  { p = a.src[8];  base = P_WR2; }
    else if (idx < P_ATT2) { p = a.src[9];  base = P_BR2; }
    else if (idx < P_BIAS2){ p = a.src[10]; base = P_ATT2; }
    else                   { p = a.src[11]; base = P_BIAS2; }
    int li = idx - base;
    par[idx] = flag ? ((const float*)p)[li] : (float)((const bf16*)p)[li];
    return;
  }
  b -= B_CVT;
  if (b < B_XP) {                        // ---- x -> xb, 8 ch/thread ----
    const int flag = detect_f32_wave(a.x);
    int gid = b * 256 + tid;
    int n = gid >> 3, k0 = (gid & 7) * 8;
    float v[8];
#pragma unroll
    for (int j = 0; j < 8; j++) {
      int k = k0 + j;
      v[j] = 0.f;
      if (k < IN_F) {
        int idx = n * IN_F + k;
        v[j] = flag ? ((const float*)a.x)[idx] : (float)((const bf16*)a.x)[idx];
      }
    }
    __align__(16) bf16 ob[8];
#pragma unroll
    for (int j = 0; j < 8; j++) ob[j] = (bf16)v[j];
    *(uint4*)(xb + (size_t)n * 64 + k0) = *(uint4*)ob;
    return;
  }
  b -= B_XP;
  if (b < B_W1) {                        // ---- Wt1[n][k] 512x64 ----
    const int flag = detect_f32_wave(a.x);
    int i = b * 256 + tid;
    int n = i >> 6, k = i & 63;
    float v = 0.f;
    if (k < IN_F) {
      const void* W = (n < F1) ? a.src[0] : a.src[2];
      int col = (n < F1) ? n : n - F1;
      int idx = k * F1 + col;
      v = flag ? ((const float*)W)[idx] : (float)((const bf16*)W)[idx];
    }
    wt1[i] = (bf16)v;
    return;
  }
  b -= B_W1;
  if (b < B_W2) {                        // ---- Wt2[n][k] 256x256 ----
    const int flag = detect_f32_wave(a.x);
    int i = b * 256 + tid;
    int n = i >> 8, k = i & 255;
    const void* W = (n < F2) ? a.src[6] : a.src[8];
    int col = (n < F2) ? n : n - F2;
    int idx = k * F2 + col;
    float v = flag ? ((const float*)W)[idx] : (float)((const bf16*)W)[idx];
    wt2[i] = (bf16)v;
    return;
  }
  b -= B_W2;
  if (b < B_BND) {                       // ---- graph bounds (+1 encoding, 0 = unset) ----
    int n = b * 256 + tid;
    if (n >= N_NODES) return;
    int bb = a.batch[n];
    if (n == 0) gs[bb] = 1;
    else {
      int bp = a.batch[n - 1];
      if (bp != bb) { gs[bb] = n + 1; ge[bp] = n; }   // ge = end-exclusive
    }
    if (n == N_NODES - 1) ge[bb] = N_NODES;
    return;
  }
  b -= B_BND;
  {                                      // ---- degree count + rank, 4 edges/thread ----
    int base = b * 1024 + tid;
    int dstv[4]; bool val[4];
#pragma unroll
    for (int i = 0; i < 4; i++) {
      int e = base + i * 256;
      val[i] = e < TOT_E;
      dstv[i] = 0;
      if (val[i])
        dstv[i] = (e < N_EDGES) ? a.ei[N_EDGES + e] : (e - N_EDGES);
    }
#pragma unroll
    for (int i = 0; i < 4; i++) {
      int e = base + i * 256;
      if (val[i]) rank[e] = atomicAdd(&cnt[dstv[i]], 1);
    }
  }
}

// ---------------- scan_a: 256 thr x 4 elems -> block-exclusive offs_p + bsum ----------------
__global__ __launch_bounds__(256) void scan_a(const int* __restrict__ cnt,
                                              int* __restrict__ offs_p,
                                              int* __restrict__ bsum) {
  __shared__ int wsum[4];
  const int t = threadIdx.x, lane = t & 63, w = t >> 6;
  int i0 = blockIdx.x * 1024 + t * 4;
  int v[4];
#pragma unroll
  for (int j = 0; j < 4; j++) v[j] = (i0 + j < N_NODES) ? cnt[i0 + j] : 0;
  int tsum = v[0] + v[1] + v[2] + v[3];
  int s = tsum;
#pragma unroll
  for (int off = 1; off < 64; off <<= 1) {
    int u = __shfl_up(s, off, 64);
    if (lane >= off) s += u;
  }
  if (lane == 63) wsum[w] = s;
  __syncthreads();
  int pref = 0;
  for (int i = 0; i < w; i++) pref += wsum[i];
  int excl = pref + s - tsum;
  int o0 = excl, o1 = o0 + v[0], o2 = o1 + v[1], o3 = o2 + v[2];
  if (i0 + 3 < N_NODES) {
    int4 q; q.x = o0; q.y = o1; q.z = o2; q.w = o3;
    *(int4*)(offs_p + i0) = q;
  } else {
    if (i0     < N_NODES) offs_p[i0]     = o0;
    if (i0 + 1 < N_NODES) offs_p[i0 + 1] = o1;
    if (i0 + 2 < N_NODES) offs_p[i0 + 2] = o2;
    if (i0 + 3 < N_NODES) offs_p[i0 + 3] = o3;
  }
  if (t == 255) bsum[blockIdx.x] = pref + s;
}

// ---------------- mega: scan_c || GEMM1 (MFMA, LDS epilogue) || scatter ----------------
// scan_c finalizes offs (for aggs); scatter uses offs_p + in-block boff (no dep on scan_c).
__global__ __launch_bounds__(256) void mega_k(
    const bf16* __restrict__ xb, const bf16* __restrict__ wt1,
    const float* __restrict__ par,
    fp8_t* __restrict__ xl1, bf16* __restrict__ xr1,
    const int* __restrict__ ei, const int* __restrict__ offs_p,
    const int* __restrict__ bsum, const int* __restrict__ rank,
    int* __restrict__ offs, int* __restrict__ csr) {
  __shared__ char lds[24576];
  __shared__ int boff_s[64];
  int b = blockIdx.x;
  const int tid = threadIdx.x;

  if (b < MEGA_SCANC) {                  // ---- scan_c: finalize offs ----
    if (tid < 64) {
      int v = (tid < SCAN_BLKS) ? bsum[tid] : 0;
      int s = v;
#pragma unroll
      for (int off = 1; off < 64; off <<= 1) {
        int u = __shfl_up(s, off, 64);
        if (tid >= off) s += u;
      }
      boff_s[tid] = s - v;
    }
    __syncthreads();
    int idx = b * 256 + tid;
    if (idx < N_NODES) offs[idx] = offs_p[idx] + boff_s[idx >> 10];
    if (b == 0 && tid == 0) offs[N_NODES] = TOT_E;
    return;
  }
  b -= MEGA_SCANC;
  if (b >= GBLK) {                       // ---- scatter (atomic-free) ----
    b -= GBLK;
    if (tid < 64) {
      int v = (tid < SCAN_BLKS) ? bsum[tid] : 0;
      int s = v;
#pragma unroll
      for (int off = 1; off < 64; off <<= 1) {
        int u = __shfl_up(s, off, 64);
        if (tid >= off) s += u;
      }
      boff_s[tid] = s - v;
    }
    __syncthreads();
    int base = b * 1024 + tid;
#pragma unroll
    for (int i = 0; i < 4; i++) {
      int e = base + i * 256;
      if (e >= TOT_E) continue;
      int src, dst;
      if (e < N_EDGES) { src = ei[e]; dst = ei[N_EDGES + e]; }
      else             { src = dst = e - N_EDGES; }
      csr[offs_p[dst] + boff_s[dst >> 10] + rank[e]] = src;
    }
    return;
  }
  // ---- gemm1 path ----
  const int w = tid >> 6, lane = tid & 63;
  const int m0 = b * 32;
  const int colbase = w * 128;
  const int lm = lane & 31;
  const int kh = lane >> 5;

  int arow = m0 + lm; if (arow >= N_NODES) arow = N_NODES - 1;
  short8 afr[4];
#pragma unroll
  for (int kk = 0; kk < 4; kk++)
    afr[kk] = *(const short8*)(xb + (size_t)arow * 64 + kk * 16 + kh * 8);

  f32x16 acc[4] = {};
#pragma unroll
  for (int t = 0; t < 4; t++) {
    int n = colbase + t * 32 + lm;
#pragma unroll
    for (int kk = 0; kk < 4; kk++) {
      short8 bb = *(const short8*)(wt1 + (size_t)n * 64 + kk * 16 + kh * 8);
      acc[t] = __builtin_amdgcn_mfma_f32_32x32x16_bf16(afr[kk], bb, acc[t], 0, 0, 0);
    }
  }

  char* lds8  = lds;                     // [32][256] fp8
  bf16* lds16 = (bf16*)(lds + 8192);     // [32][256] bf16
  if (w < 2) {
#pragma unroll
    for (int t = 0; t < 4; t++) {
      int col = colbase + t * 32 + lm;
      float bv = par[P_BL1 + col];
#pragma unroll
      for (int reg = 0; reg < 16; reg++) {
        int rl = (reg & 3) + 8 * (reg >> 2) + 4 * kh;
        lds8[rl * 256 + col] = f32_to_fp8(acc[t][reg] + bv);
      }
    }
  } else {
#pragma unroll
    for (int t = 0; t < 4; t++) {
      int c = colbase - 256 + t * 32 + lm;
      float bv = par[P_BR1 + c];
#pragma unroll
      for (int reg = 0; reg < 16; reg++) {
        int rl = (reg & 3) + 8 * (reg >> 2) + 4 * kh;
        lds16[rl * 256 + c] = (bf16)(acc[t][reg] + bv);
      }
    }
  }
  __syncthreads();

#pragma unroll
  for (int i = 0; i < 2; i++) {          // xl1: 32 rows x 256B
    int idx = tid + i * 256;
    int row = idx >> 4, ck = (idx & 15) * 16;
    int grow = m0 + row;
    if (grow < N_NODES)
      *(uint4*)(xl1 + (size_t)grow * F1 + ck) = *(uint4*)(lds8 + row * 256 + ck);
  }
#pragma unroll
  for (int i = 0; i < 4; i++) {          // xr1: 32 rows x 512B
    int idx = tid + i * 256;
    int row = idx >> 5, ck = (idx & 31) * 16;
    int grow = m0 + row;
    if (grow < N_NODES)
      *(uint4*)((char*)(xr1 + (size_t)grow * F1) + ck) =
          *(uint4*)((char*)(lds16 + row * 256) + ck);
  }
}

// ---------------- GEMM 2 (MFMA 32x32x16, LDS-staged epilogue) ----------------
__global__ __launch_bounds__(256) void gemm2_mfma_k(
    const bf16* __restrict__ h, const bf16* __restrict__ wt2,
    const float* __restrict__ par,
    fp8_t* __restrict__ xl2, bf16* __restrict__ xr2) {
  __shared__ char lds[12288];
  const int w = threadIdx.x >> 6, lane = threadIdx.x & 63;
  const int m0 = blockIdx.x * 32;
  const int colbase = w * 64;
  const int lm = lane & 31;
  const int kh = lane >> 5;

  int arow = m0 + lm; if (arow >= N_NODES) arow = N_NODES - 1;
  const bf16* hrow = h + (size_t)arow * F1 + kh * 8;

  f32x16 acc[2] = {};
#pragma unroll
  for (int kk = 0; kk < 16; kk++) {
    short8 a = *(const short8*)(hrow + kk * 16);
#pragma unroll
    for (int t = 0; t < 2; t++) {
      int n = colbase + t * 32 + lm;
      short8 b = *(const short8*)(wt2 + (size_t)n * 256 + kk * 16 + kh * 8);
      acc[t] = __builtin_amdgcn_mfma_f32_32x32x16_bf16(a, b, acc[t], 0, 0, 0);
    }
  }

  char* lds8  = lds;                     // [32][128] fp8
  bf16* lds16 = (bf16*)(lds + 4096);     // [32][128] bf16
  if (w < 2) {
#pragma unroll
    for (int t = 0; t < 2; t++) {
      int col = colbase + t * 32 + lm;
      float bv = par[P_BL2 + col];
#pragma unroll
      for (int reg = 0; reg < 16; reg++) {
        int rl = (reg & 3) + 8 * (reg >> 2) + 4 * kh;
        lds8[rl * 128 + col] = f32_to_fp8(acc[t][reg] + bv);
      }
    }
  } else {
#pragma unroll
    for (int t = 0; t < 2; t++) {
      int c = colbase - 128 + t * 32 + lm;
      float bv = par[P_BR2 + c];
#pragma unroll
      for (int reg = 0; reg < 16; reg++) {
        int rl = (reg & 3) + 8 * (reg >> 2) + 4 * kh;
        lds16[rl * 128 + c] = (bf16)(acc[t][reg] + bv);
      }
    }
  }
  __syncthreads();

  const int tid = threadIdx.x;
  {
    int row = tid >> 3, ck = (tid & 7) * 16;
    int grow = m0 + row;
    if (grow < N_NODES)
      *(uint4*)(xl2 + (size_t)grow * F2 + ck) = *(uint4*)(lds8 + row * 128 + ck);
  }
#pragma unroll
  for (int i = 0; i < 2; i++) {
    int idx = tid + i * 256;
    int row = idx >> 4, ck = (idx & 15) * 16;
    int grow = m0 + row;
    if (grow < N_NODES)
      *(uint4*)((char*)(xr2 + (size_t)grow * F2) + ck) =
          *(uint4*)((char*)(lds16 + row * 128) + ck);
  }
}

// ---------------- layer-1 aggregation (R14 shape) ----------------
__global__ __launch_bounds__(256, 4) void agg1_k(
    const fp8_t* __restrict__ xl1, const bf16* __restrict__ xr1,
    const float* __restrict__ par,
    const int* __restrict__ offs, const int* __restrict__ csr,
    bf16* __restrict__ hout) {
  const int dst = blockIdx.x * 4 + (threadIdx.x >> 6);
  if (dst >= N_NODES) return;
  const int lane = threadIdx.x & 63;
  const int g = lane >> 5;
  const int sl = lane & 31;
  const int chb = sl * 8;

  f2 r2[4], a2[4];
  load8bf2(xr1 + (size_t)dst * F1 + chb, r2);
  {
    float4 aa = *(const float4*)(par + P_ATT1 + chb);
    float4 ab = *(const float4*)(par + P_ATT1 + chb + 4);
    a2[0].x = aa.x; a2[0].y = aa.y; a2[1].x = aa.z; a2[1].y = aa.w;
    a2[2].x = ab.x; a2[2].y = ab.y; a2[3].x = ab.z; a2[3].y = ab.w;
  }

  const int e0 = offs[dst], e1 = offs[dst + 1];
  const f2 zf2 = {0.f, 0.f};
  f2 acc2[4];
#pragma unroll
  for (int j = 0; j < 4; j++) acc2[j] = zf2;
  float denom = 0.f;

  const uint2 zq = {0, 0};
  int e = e0 + g;
  bool valid = e < e1;
  uint2 q = valid ? *(const uint2*)(xl1 + (size_t)csr[e] * F1 + chb) : zq;

  for (int base = e0; base < e1; base += 2) {
    const uint2 qc = q;
    const bool vc = valid;
    e += 2;
    valid = e < e1;
    q = valid ? *(const uint2*)(xl1 + (size_t)csr[e] * F1 + chb) : zq;

    f2 v2[4];
    unpack8fp8(qc, v2);
    f2 lt2 = zf2;
#pragma unroll
    for (int j = 0; j < 4; j++)
      lt2 = lrelu2(v2[j] + r2[j]) * a2[j] + lt2;
    float lt = vc ? (lt2.x + lt2.y) : -1e30f;
    lt += __shfl_xor(lt, 1, 64);
    lt += __shfl_xor(lt, 2, 64);
    lt += __shfl_xor(lt, 4, 64);
    float p = __expf(fminf(lt, 60.f));
    denom += p;
    f2 pv; pv.x = p; pv.y = p;
#pragma unroll
    for (int j = 0; j < 4; j++) acc2[j] = pv * v2[j] + acc2[j];
  }

  denom += __shfl_xor(denom, 32, 64);
#pragma unroll
  for (int j = 0; j < 4; j++) {
    acc2[j].x += __shfl_xor(acc2[j].x, 32, 64);
    acc2[j].y += __shfl_xor(acc2[j].y, 32, 64);
  }

  if (g == 0) {
    float inv = 1.f / (denom + EPS_A);
    __align__(16) bf16 ob[8];
#pragma unroll
    for (int j = 0; j < 4; j++) {
      float o0 = fmaxf(acc2[j].x * inv + par[P_BIAS1 + chb + 2*j],     0.f);
      float o1 = fmaxf(acc2[j].y * inv + par[P_BIAS1 + chb + 2*j + 1], 0.f);
      ob[2*j] = (bf16)o0; ob[2*j+1] = (bf16)o1;
    }
    *(uint4*)(hout + (size_t)dst * F1 + chb) = *(uint4*)ob;
  }
}

// ---------------- layer-2 aggregation (R14 shape) ----------------
__global__ __launch_bounds__(256, 4) void agg2_k(
    const fp8_t* __restrict__ xl2, const bf16* __restrict__ xr2,
    const float* __restrict__ par,
    const int* __restrict__ offs, const int* __restrict__ csr,
    bf16* __restrict__ h2) {
  const int dst = blockIdx.x * 4 + (threadIdx.x >> 6);
  if (dst >= N_NODES) return;
  const int lane = threadIdx.x & 63;
  const int g = lane >> 4;
  const int sl = lane & 15;
  const int chb = sl * 8;

  f2 r2[4], a2[4];
  load8bf2(xr2 + (size_t)dst * F2 + chb, r2);
  {
    float4 aa = *(const float4*)(par + P_ATT2 + chb);
    float4 ab = *(const float4*)(par + P_ATT2 + chb + 4);
    a2[0].x = aa.x; a2[0].y = aa.y; a2[1].x = aa.z; a2[1].y = aa.w;
    a2[2].x = ab.x; a2[2].y = ab.y; a2[3].x = ab.z; a2[3].y = ab.w;
  }

  const int e0 = offs[dst], e1 = offs[dst + 1];
  const f2 zf2 = {0.f, 0.f};
  f2 acc2[4];
#pragma unroll
  for (int j = 0; j < 4; j++) acc2[j] = zf2;
  float denom = 0.f;

  const uint2 zq = {0, 0};
  int e = e0 + g;
  bool valid = e < e1;
  uint2 q = valid ? *(const uint2*)(xl2 + (size_t)csr[e] * F2 + chb) : zq;

  for (int base = e0; base < e1; base += 4) {
    const uint2 qc = q;
    const bool vc = valid;
    e += 4;
    valid = e < e1;
    q = valid ? *(const uint2*)(xl2 + (size_t)csr[e] * F2 + chb) : zq;

    f2 v2[4];
    unpack8fp8(qc, v2);
    f2 lt2 = zf2;
#pragma unroll
    for (int j = 0; j < 4; j++)
      lt2 = lrelu2(v2[j] + r2[j]) * a2[j] + lt2;
    float lt = vc ? (lt2.x + lt2.y) : -1e30f;
    lt += __shfl_xor(lt, 1, 64);
    lt += __shfl_xor(lt, 2, 64);
    lt += __shfl_xor(lt, 4, 64);
    lt += __shfl_xor(lt, 8, 64);
    float p = __expf(fminf(lt, 60.f));
    denom += p;
    f2 pv; pv.x = p; pv.y = p;
#pragma unroll
    for (int j = 0; j < 4; j++) acc2[j] = pv * v2[j] + acc2[j];
  }

#pragma unroll
  for (int m = 16; m <= 32; m <<= 1) {
    denom += __shfl_xor(denom, m, 64);
#pragma unroll
    for (int j = 0; j < 4; j++) {
      acc2[j].x += __shfl_xor(acc2[j].x, m, 64);
      acc2[j].y += __shfl_xor(acc2[j].y, m, 64);
    }
  }

  if (g == 0) {
    float inv = 1.f / (denom + EPS_A);
    __align__(16) bf16 ob[8];
#pragma unroll
    for (int j = 0; j < 4; j++) {
      float o0 = fmaxf(acc2[j].x * inv + par[P_BIAS2 + chb + 2*j],     0.f);
      float o1 = fmaxf(acc2[j].y * inv + par[P_BIAS2 + chb + 2*j + 1], 0.f);
      ob[2*j] = (bf16)o0; ob[2*j+1] = (bf16)o1;
    }
    *(uint4*)(h2 + (size_t)dst * F2 + chb) = *(uint4*)ob;
  }
}

// ---------------- pooling: 8 slices/graph, last-arriver finalizes ----------------
__global__ __launch_bounds__(256) void poolp_k(
    const bf16* __restrict__ h2, const int* __restrict__ gs,
    const int* __restrict__ ge, float* __restrict__ psum,
    int* __restrict__ done, const void* __restrict__ x,
    void* __restrict__ out) {
  const int g = blockIdx.x >> 3, slice = blockIdx.x & 7;
  const int t = threadIdx.x;
  const int c = t & 127, half = t >> 7;
  const int s = gs[g] - 1, eex = ge[g];    // +1 encoding; 0 = unset
  const bool nonempty = (s >= 0 && eex > s);
  float sum = 0.f;
  if (nonempty)
    for (int n = s + slice * 2 + half; n < eex; n += 16)
      sum += (float)h2[(size_t)n * F2 + c];
  atomicAdd(&psum[g * F2 + c], sum);

  __threadfence();
  __shared__ int lastflag;
  if (t == 0) lastflag = (atomicAdd(&done[g], 1) == 7);
  __syncthreads();
  if (lastflag) {
    __threadfence();
    const int flag = detect_f32_wave(x);
    if (t < F2) {
      int i = g * F2 + t;
      float cntf = nonempty ? (float)(eex - s) : 1.f;
      volatile const float* vp = psum;
      float v = vp[i] / cntf;
      if (flag) ((float*)out)[i] = v;
      else      ((bf16*)out)[i] = (bf16)v;
    }
  }
}

// ---------------- launch ----------------
extern "C" void kernel_launch(void* const* d_in, const int* in_sizes, int n_in,
                              void* d_out, int out_size, void* d_ws, size_t ws_size,
                              hipStream_t stream) {
  (void)in_sizes; (void)n_in; (void)out_size; (void)ws_size;
  const void* x     = d_in[0];
  const int*  ei    = (const int*)d_in[1];
  const int*  batch = (const int*)d_in[2];

  char* ws = (char*)d_ws;
  float* par  = (float*)(ws + OFF_PAR);
  fp8_t* xl1 = (fp8_t*)(ws + OFF_XL1);
  bf16* xr1 = (bf16*)(ws + OFF_XR1);
  bf16* h   = (bf16*)(ws + OFF_H);
  fp8_t* xl2 = (fp8_t*)(ws + OFF_XL2);
  bf16* xr2 = (bf16*)(ws + OFF_XR2);
  bf16* h2  = (bf16*)(ws + OFF_H2);
  bf16* xb  = (bf16*)(ws + OFF_XB);
  bf16* wt1 = (bf16*)(ws + OFF_WT1);
  bf16* wt2 = (bf16*)(ws + OFF_WT2);
  int* cnt    = (int*)(ws + OFF_CNT);
  int* offs   = (int*)(ws + OFF_OFFS);
  int* offs_p = (int*)(ws + OFF_OFFSP);
  int* csr    = (int*)(ws + OFF_CSR);
  int* gs     = (int*)(ws + OFF_GS);
  int* ge     = (int*)(ws + OFF_GE);
  int* bsum   = (int*)(ws + OFF_BS);
  float* psum = (float*)(ws + OFF_PSUM);
  int* done   = (int*)(ws + OFF_DONE);
  int* rank   = (int*)(ws + OFF_RANK);

  // single zero-init: cnt | gs | ge | psum | done (contiguous)
  hipMemsetAsync(cnt, 0, OFF_ZEND - OFF_CNT, stream);

  PrepArgs pa;
  pa.x = x; pa.ei = ei; pa.batch = batch;
  for (int i = 0; i < 12; i++) pa.src[i] = d_in[3 + i];
  const int prep_blocks = B_CVT + B_XP + B_W1 + B_W2 + B_BND + B_CNT;
  prep_k<<<prep_blocks, 256, 0, stream>>>(pa, par, xb, wt1, wt2, gs, ge, cnt, rank);

  scan_a<<<SCAN_BLKS, 256, 0, stream>>>(cnt, offs_p, bsum);

  mega_k<<<MEGA_SCANC + GBLK + SBL, 256, 0, stream>>>(
      xb, wt1, par, xl1, xr1, ei, offs_p, bsum, rank, offs, csr);

  agg1_k<<<(N_NODES + 3) / 4, 256, 0, stream>>>(xl1, xr1, par, offs, csr, h);
  gemm2_mfma_k<<<GBLK, 256, 0, stream>>>(h, wt2, par, xl2, xr2);
  agg2_k<<<(N_NODES + 3) / 4, 256, 0, stream>>>(xl2, xr2, par, offs, csr, h2);
  poolp_k<<<NGRAPH * 8, 256, 0, stream>>>(h2, gs, ge, psum, done, x, d_out);
}

// Round 19
// 315.982 us; speedup vs baseline: 1.2386x; 1.2386x over previous
//
#include <hip/hip_runtime.h>
#include <hip/hip_bf16.h>
#include <limits.h>

// ---------------- problem constants ----------------
#define N_NODES 50000
#define N_EDGES 800000
#define TOT_E   (N_EDGES + N_NODES)   // with self loops
#define IN_F    38
#define HIDC    64
#define NH      4
#define F1      256                    // NH*HIDC
#define F2      128                    // OUT
#define NGRAPH  128
#define NEG_SLOPE 0.2f
#define EPS_A   1e-16f

typedef __hip_bfloat16 bf16;
typedef unsigned char fp8_t;           // OCP e4m3 raw byte
typedef __attribute__((ext_vector_type(8))) short short8;
typedef __attribute__((ext_vector_type(16))) float f32x16;
typedef __attribute__((ext_vector_type(2))) float f2;   // lowers to VOP3P v_pk_*_f32

// ---------------- ws layout ----------------
constexpr size_t al256(size_t x) { return (x + 255) & ~(size_t)255; }

// converted-params element offsets (f32 elements)
#define P_WL1   0
#define P_BL1   (P_WL1 + IN_F * F1)
#define P_WR1   (P_BL1 + F1)
#define P_BR1   (P_WR1 + IN_F * F1)
#define P_ATT1  (P_BR1 + F1)
#define P_BIAS1 (P_ATT1 + F1)
#define P_WL2   (P_BIAS1 + F1)
#define P_BL2   (P_WL2 + F1 * F2)
#define P_WR2   (P_BL2 + F2)
#define P_BR2   (P_WR2 + F1 * F2)
#define P_ATT2  (P_BR2 + F2)
#define P_BIAS2 (P_ATT2 + F2)
#define P_TOTAL (P_BIAS2 + F2)         // 86528 = 338*256

constexpr size_t OFF_PAR  = 256;
constexpr size_t OFF_XL1  = OFF_PAR + al256((size_t)P_TOTAL * 4);   // fp8 N*256; reused as h2
constexpr size_t OFF_XR1  = OFF_XL1 + al256((size_t)N_NODES * F1 * 2);
constexpr size_t OFF_H    = OFF_XR1 + al256((size_t)N_NODES * F1 * 2);
constexpr size_t OFF_XL2  = OFF_H   + al256((size_t)N_NODES * F1 * 2);  // fp8 N*128
constexpr size_t OFF_XR2  = OFF_XL2 + al256((size_t)N_NODES * F2 * 2);
// --- zero-init region (single memset): cnt | gs | ge | psum ---
constexpr size_t OFF_CNT  = OFF_XR2 + al256((size_t)N_NODES * F2 * 2);
constexpr size_t OFF_GS   = OFF_CNT + al256((size_t)N_NODES * 4);
constexpr size_t OFF_GE   = OFF_GS  + al256((size_t)NGRAPH * 4);
constexpr size_t OFF_PSUM = OFF_GE  + al256((size_t)NGRAPH * 4);
constexpr size_t OFF_ZEND = OFF_PSUM+ al256((size_t)NGRAPH * F2 * 4);
// --- rest ---
constexpr size_t OFF_OFFS = OFF_ZEND;                               // final (N+1)
constexpr size_t OFF_OFFSP= OFF_OFFS+ al256((size_t)(N_NODES + 1) * 4); // partial (N)
constexpr size_t OFF_CSR  = OFF_OFFSP+ al256((size_t)N_NODES * 4);
constexpr size_t OFF_WT1  = OFF_CSR + al256((size_t)TOT_E * 4);     // 512x64 bf16
constexpr size_t OFF_WT2  = OFF_WT1 + al256((size_t)512 * 64 * 2);  // 256x256 bf16
constexpr size_t OFF_BS   = OFF_WT2 + al256((size_t)256 * 256 * 2); // 49 block sums
constexpr size_t OFF_RANK = OFF_BS  + al256(64 * 4);                // per-edge rank
constexpr size_t OFF_H2   = OFF_XL1;  // xl1 dead after agg1
constexpr size_t OFF_XB   = OFF_H;    // xb dead before agg1 writes h

#define SCAN_BLKS 49   // ceil(50000/1024)
#define GBLK 1563      // ceil(50000/32)
#define SBL  831       // ceil(TOT_E/1024)
#define MEGA_SCANC 196 // scan_c blocks inside mega_k

// ---------------- helpers ----------------
__device__ __forceinline__ void unpack8bf2(uint4 q, f2* f) {
  unsigned v[4] = {q.x, q.y, q.z, q.w};
#pragma unroll
  for (int i = 0; i < 4; i++) {
    f2 t;
    t.x = __uint_as_float(v[i] << 16);
    t.y = __uint_as_float(v[i] & 0xffff0000u);
    f[i] = t;
  }
}

__device__ __forceinline__ void load8bf2(const bf16* __restrict__ p, f2* f) {
  unpack8bf2(*(const uint4*)p, f);
}

// 8 fp8 bytes -> 4 x f2 via HW v_cvt_pk_f32_fp8
__device__ __forceinline__ void unpack8fp8(uint2 q, f2* f) {
  f[0] = __builtin_amdgcn_cvt_pk_f32_fp8(q.x, false);
  f[1] = __builtin_amdgcn_cvt_pk_f32_fp8(q.x, true);
  f[2] = __builtin_amdgcn_cvt_pk_f32_fp8(q.y, false);
  f[3] = __builtin_amdgcn_cvt_pk_f32_fp8(q.y, true);
}

__device__ __forceinline__ fp8_t f32_to_fp8(float v) {
  return (fp8_t)(__builtin_amdgcn_cvt_pk_fp8_f32(v, v, 0, false) & 0xFF);
}

// leaky_relu(s) = 0.6*s + 0.4*|s|
__device__ __forceinline__ f2 lrelu2(f2 s) {
  f2 as;
  as.x = __uint_as_float(__float_as_uint(s.x) & 0x7fffffffu);
  as.y = __uint_as_float(__float_as_uint(s.y) & 0x7fffffffu);
  return 0.6f * s + 0.4f * as;
}

// wave-cooperative dtype sniff: 1 = inputs are f32, 0 = bf16.
__device__ __forceinline__ int detect_f32_wave(const void* __restrict__ x) {
  const unsigned short* u = (const unsigned short*)x;
  unsigned short b = u[threadIdx.x & 63];
  int e = (b >> 7) & 0xFF;
  unsigned long long m = __ballot(!((e == 0) || (e >= 96 && e <= 158)));
  return __popcll(m) > 8;
}

// ---------------- fused prep kernel (MLP-widened) ----------------
#define B_CVT  338
#define B_XP   1563    // 8 channels/thread
#define B_W1   128
#define B_W2   256
#define B_BND  196
#define B_CNT  831     // 4 edges/thread

struct PrepArgs {
  const void* x;
  const void* src[12];
  const int* ei;
  const int* batch;
};

__global__ __launch_bounds__(256) void prep_k(
    PrepArgs a, float* __restrict__ par, bf16* __restrict__ xb,
    bf16* __restrict__ wt1, bf16* __restrict__ wt2,
    int* __restrict__ gs, int* __restrict__ ge, int* __restrict__ cnt,
    int* __restrict__ rank) {
  int b = blockIdx.x;
  const int tid = threadIdx.x;

  if (b < B_CVT) {                       // ---- param convert -> f32 ----
    const int flag = detect_f32_wave(a.x);
    int idx = b * 256 + tid;
    const void* p; int base;
    if      (idx < P_BL1)  { p = a.src[0];  base = P_WL1; }
    else if (idx < P_WR1)  { p = a.src[1];  base = P_BL1; }
    else if (idx < P_BR1)  { p = a.src[2];  base = P_WR1; }
    else if (idx < P_ATT1) { p = a.src[3];  base = P_BR1; }
    else if (idx < P_BIAS1){ p = a.src[4];  base = P_ATT1; }
    else if (idx < P_WL2)  { p = a.src[5];  base = P_BIAS1; }
    else if (idx < P_BL2)  { p = a.src[6];  base = P_WL2; }
    else if (idx < P_WR2)  { p = a.src[7];  base = P_BL2; }
    else if (idx < P_BR2)  { p = a.src[8];  base = P_WR2; }
    else if (idx < P_ATT2) { p = a.src[9];  base = P_BR2; }
    else if (idx < P_BIAS2){ p = a.src[10]; base = P_ATT2; }
    else                   { p = a.src[11]; base = P_BIAS2; }
    int li = idx - base;
    par[idx] = flag ? ((const float*)p)[li] : (float)((const bf16*)p)[li];
    return;
  }
  b -= B_CVT;
  if (b < B_XP) {                        // ---- x -> xb, 8 ch/thread ----
    const int flag = detect_f32_wave(a.x);
    int gid = b * 256 + tid;
    int n = gid >> 3, k0 = (gid & 7) * 8;
    float v[8];
#pragma unroll
    for (int j = 0; j < 8; j++) {
      int k = k0 + j;
      v[j] = 0.f;
      if (k < IN_F) {
        int idx = n * IN_F + k;
        v[j] = flag ? ((const float*)a.x)[idx] : (float)((const bf16*)a.x)[idx];
      }
    }
    __align__(16) bf16 ob[8];
#pragma unroll
    for (int j = 0; j < 8; j++) ob[j] = (bf16)v[j];
    *(uint4*)(xb + (size_t)n * 64 + k0) = *(uint4*)ob;
    return;
  }
  b -= B_XP;
  if (b < B_W1) {                        // ---- Wt1[n][k] 512x64 ----
    const int flag = detect_f32_wave(a.x);
    int i = b * 256 + tid;
    int n = i >> 6, k = i & 63;
    float v = 0.f;
    if (k < IN_F) {
      const void* W = (n < F1) ? a.src[0] : a.src[2];
      int col = (n < F1) ? n : n - F1;
      int idx = k * F1 + col;
      v = flag ? ((const float*)W)[idx] : (float)((const bf16*)W)[idx];
    }
    wt1[i] = (bf16)v;
    return;
  }
  b -= B_W1;
  if (b < B_W2) {                        // ---- Wt2[n][k] 256x256 ----
    const int flag = detect_f32_wave(a.x);
    int i = b * 256 + tid;
    int n = i >> 8, k = i & 255;
    const void* W = (n < F2) ? a.src[6] : a.src[8];
    int col = (n < F2) ? n : n - F2;
    int idx = k * F2 + col;
    float v = flag ? ((const float*)W)[idx] : (float)((const bf16*)W)[idx];
    wt2[i] = (bf16)v;
    return;
  }
  b -= B_W2;
  if (b < B_BND) {                       // ---- graph bounds (+1 encoding, 0 = unset) ----
    int n = b * 256 + tid;
    if (n >= N_NODES) return;
    int bb = a.batch[n];
    if (n == 0) gs[bb] = 1;
    else {
      int bp = a.batch[n - 1];
      if (bp != bb) { gs[bb] = n + 1; ge[bp] = n; }   // ge = end-exclusive
    }
    if (n == N_NODES - 1) ge[bb] = N_NODES;
    return;
  }
  b -= B_BND;
  {                                      // ---- degree count + rank, 4 edges/thread ----
    int base = b * 1024 + tid;
    int dstv[4]; bool val[4];
#pragma unroll
    for (int i = 0; i < 4; i++) {
      int e = base + i * 256;
      val[i] = e < TOT_E;
      dstv[i] = 0;
      if (val[i])
        dstv[i] = (e < N_EDGES) ? a.ei[N_EDGES + e] : (e - N_EDGES);
    }
#pragma unroll
    for (int i = 0; i < 4; i++) {
      int e = base + i * 256;
      if (val[i]) rank[e] = atomicAdd(&cnt[dstv[i]], 1);
    }
  }
}

// ---------------- scan_a: 256 thr x 4 elems -> block-exclusive offs_p + bsum ----------------
__global__ __launch_bounds__(256) void scan_a(const int* __restrict__ cnt,
                                              int* __restrict__ offs_p,
                                              int* __restrict__ bsum) {
  __shared__ int wsum[4];
  const int t = threadIdx.x, lane = t & 63, w = t >> 6;
  int i0 = blockIdx.x * 1024 + t * 4;
  int v[4];
#pragma unroll
  for (int j = 0; j < 4; j++) v[j] = (i0 + j < N_NODES) ? cnt[i0 + j] : 0;
  int tsum = v[0] + v[1] + v[2] + v[3];
  int s = tsum;
#pragma unroll
  for (int off = 1; off < 64; off <<= 1) {
    int u = __shfl_up(s, off, 64);
    if (lane >= off) s += u;
  }
  if (lane == 63) wsum[w] = s;
  __syncthreads();
  int pref = 0;
  for (int i = 0; i < w; i++) pref += wsum[i];
  int excl = pref + s - tsum;
  int o0 = excl, o1 = o0 + v[0], o2 = o1 + v[1], o3 = o2 + v[2];
  if (i0 + 3 < N_NODES) {
    int4 q; q.x = o0; q.y = o1; q.z = o2; q.w = o3;
    *(int4*)(offs_p + i0) = q;
  } else {
    if (i0     < N_NODES) offs_p[i0]     = o0;
    if (i0 + 1 < N_NODES) offs_p[i0 + 1] = o1;
    if (i0 + 2 < N_NODES) offs_p[i0 + 2] = o2;
    if (i0 + 3 < N_NODES) offs_p[i0 + 3] = o3;
  }
  if (t == 255) bsum[blockIdx.x] = pref + s;
}

// ---------------- mega: scan_c || GEMM1 (MFMA, LDS epilogue) || scatter ----------------
__global__ __launch_bounds__(256) void mega_k(
    const bf16* __restrict__ xb, const bf16* __restrict__ wt1,
    const float* __restrict__ par,
    fp8_t* __restrict__ xl1, bf16* __restrict__ xr1,
    const int* __restrict__ ei, const int* __restrict__ offs_p,
    const int* __restrict__ bsum, const int* __restrict__ rank,
    int* __restrict__ offs, int* __restrict__ csr) {
  __shared__ char lds[24576];
  __shared__ int boff_s[64];
  int b = blockIdx.x;
  const int tid = threadIdx.x;

  if (b < MEGA_SCANC) {                  // ---- scan_c: finalize offs ----
    if (tid < 64) {
      int v = (tid < SCAN_BLKS) ? bsum[tid] : 0;
      int s = v;
#pragma unroll
      for (int off = 1; off < 64; off <<= 1) {
        int u = __shfl_up(s, off, 64);
        if (tid >= off) s += u;
      }
      boff_s[tid] = s - v;
    }
    __syncthreads();
    int idx = b * 256 + tid;
    if (idx < N_NODES) offs[idx] = offs_p[idx] + boff_s[idx >> 10];
    if (b == 0 && tid == 0) offs[N_NODES] = TOT_E;
    return;
  }
  b -= MEGA_SCANC;
  if (b >= GBLK) {                       // ---- scatter (atomic-free) ----
    b -= GBLK;
    if (tid < 64) {
      int v = (tid < SCAN_BLKS) ? bsum[tid] : 0;
      int s = v;
#pragma unroll
      for (int off = 1; off < 64; off <<= 1) {
        int u = __shfl_up(s, off, 64);
        if (tid >= off) s += u;
      }
      boff_s[tid] = s - v;
    }
    __syncthreads();
    int base = b * 1024 + tid;
#pragma unroll
    for (int i = 0; i < 4; i++) {
      int e = base + i * 256;
      if (e >= TOT_E) continue;
      int src, dst;
      if (e < N_EDGES) { src = ei[e]; dst = ei[N_EDGES + e]; }
      else             { src = dst = e - N_EDGES; }
      csr[offs_p[dst] + boff_s[dst >> 10] + rank[e]] = src;
    }
    return;
  }
  // ---- gemm1 path ----
  const int w = tid >> 6, lane = tid & 63;
  const int m0 = b * 32;
  const int colbase = w * 128;
  const int lm = lane & 31;
  const int kh = lane >> 5;

  int arow = m0 + lm; if (arow >= N_NODES) arow = N_NODES - 1;
  short8 afr[4];
#pragma unroll
  for (int kk = 0; kk < 4; kk++)
    afr[kk] = *(const short8*)(xb + (size_t)arow * 64 + kk * 16 + kh * 8);

  f32x16 acc[4] = {};
#pragma unroll
  for (int t = 0; t < 4; t++) {
    int n = colbase + t * 32 + lm;
#pragma unroll
    for (int kk = 0; kk < 4; kk++) {
      short8 bb = *(const short8*)(wt1 + (size_t)n * 64 + kk * 16 + kh * 8);
      acc[t] = __builtin_amdgcn_mfma_f32_32x32x16_bf16(afr[kk], bb, acc[t], 0, 0, 0);
    }
  }

  char* lds8  = lds;                     // [32][256] fp8
  bf16* lds16 = (bf16*)(lds + 8192);     // [32][256] bf16
  if (w < 2) {
#pragma unroll
    for (int t = 0; t < 4; t++) {
      int col = colbase + t * 32 + lm;
      float bv = par[P_BL1 + col];
#pragma unroll
      for (int reg = 0; reg < 16; reg++) {
        int rl = (reg & 3) + 8 * (reg >> 2) + 4 * kh;
        lds8[rl * 256 + col] = f32_to_fp8(acc[t][reg] + bv);
      }
    }
  } else {
#pragma unroll
    for (int t = 0; t < 4; t++) {
      int c = colbase - 256 + t * 32 + lm;
      float bv = par[P_BR1 + c];
#pragma unroll
      for (int reg = 0; reg < 16; reg++) {
        int rl = (reg & 3) + 8 * (reg >> 2) + 4 * kh;
        lds16[rl * 256 + c] = (bf16)(acc[t][reg] + bv);
      }
    }
  }
  __syncthreads();

#pragma unroll
  for (int i = 0; i < 2; i++) {          // xl1: 32 rows x 256B
    int idx = tid + i * 256;
    int row = idx >> 4, ck = (idx & 15) * 16;
    int grow = m0 + row;
    if (grow < N_NODES)
      *(uint4*)(xl1 + (size_t)grow * F1 + ck) = *(uint4*)(lds8 + row * 256 + ck);
  }
#pragma unroll
  for (int i = 0; i < 4; i++) {          // xr1: 32 rows x 512B
    int idx = tid + i * 256;
    int row = idx >> 5, ck = (idx & 31) * 16;
    int grow = m0 + row;
    if (grow < N_NODES)
      *(uint4*)((char*)(xr1 + (size_t)grow * F1) + ck) =
          *(uint4*)((char*)(lds16 + row * 256) + ck);
  }
}

// ---------------- GEMM 2 (MFMA 32x32x16, LDS-staged epilogue) ----------------
__global__ __launch_bounds__(256) void gemm2_mfma_k(
    const bf16* __restrict__ h, const bf16* __restrict__ wt2,
    const float* __restrict__ par,
    fp8_t* __restrict__ xl2, bf16* __restrict__ xr2) {
  __shared__ char lds[12288];
  const int w = threadIdx.x >> 6, lane = threadIdx.x & 63;
  const int m0 = blockIdx.x * 32;
  const int colbase = w * 64;
  const int lm = lane & 31;
  const int kh = lane >> 5;

  int arow = m0 + lm; if (arow >= N_NODES) arow = N_NODES - 1;
  const bf16* hrow = h + (size_t)arow * F1 + kh * 8;

  f32x16 acc[2] = {};
#pragma unroll
  for (int kk = 0; kk < 16; kk++) {
    short8 a = *(const short8*)(hrow + kk * 16);
#pragma unroll
    for (int t = 0; t < 2; t++) {
      int n = colbase + t * 32 + lm;
      short8 b = *(const short8*)(wt2 + (size_t)n * 256 + kk * 16 + kh * 8);
      acc[t] = __builtin_amdgcn_mfma_f32_32x32x16_bf16(a, b, acc[t], 0, 0, 0);
    }
  }

  char* lds8  = lds;                     // [32][128] fp8
  bf16* lds16 = (bf16*)(lds + 4096);     // [32][128] bf16
  if (w < 2) {
#pragma unroll
    for (int t = 0; t < 2; t++) {
      int col = colbase + t * 32 + lm;
      float bv = par[P_BL2 + col];
#pragma unroll
      for (int reg = 0; reg < 16; reg++) {
        int rl = (reg & 3) + 8 * (reg >> 2) + 4 * kh;
        lds8[rl * 128 + col] = f32_to_fp8(acc[t][reg] + bv);
      }
    }
  } else {
#pragma unroll
    for (int t = 0; t < 2; t++) {
      int c = colbase - 128 + t * 32 + lm;
      float bv = par[P_BR2 + c];
#pragma unroll
      for (int reg = 0; reg < 16; reg++) {
        int rl = (reg & 3) + 8 * (reg >> 2) + 4 * kh;
        lds16[rl * 128 + c] = (bf16)(acc[t][reg] + bv);
      }
    }
  }
  __syncthreads();

  const int tid = threadIdx.x;
  {
    int row = tid >> 3, ck = (tid & 7) * 16;
    int grow = m0 + row;
    if (grow < N_NODES)
      *(uint4*)(xl2 + (size_t)grow * F2 + ck) = *(uint4*)(lds8 + row * 128 + ck);
  }
#pragma unroll
  for (int i = 0; i < 2; i++) {
    int idx = tid + i * 256;
    int row = idx >> 4, ck = (idx & 15) * 16;
    int grow = m0 + row;
    if (grow < N_NODES)
      *(uint4*)((char*)(xr2 + (size_t)grow * F2) + ck) =
          *(uint4*)((char*)(lds16 + row * 128) + ck);
  }
}

// ---------------- layer-1 aggregation (R14 shape) ----------------
__global__ __launch_bounds__(256, 4) void agg1_k(
    const fp8_t* __restrict__ xl1, const bf16* __restrict__ xr1,
    const float* __restrict__ par,
    const int* __restrict__ offs, const int* __restrict__ csr,
    bf16* __restrict__ hout) {
  const int dst = blockIdx.x * 4 + (threadIdx.x >> 6);
  if (dst >= N_NODES) return;
  const int lane = threadIdx.x & 63;
  const int g = lane >> 5;
  const int sl = lane & 31;
  const int chb = sl * 8;

  f2 r2[4], a2[4];
  load8bf2(xr1 + (size_t)dst * F1 + chb, r2);
  {
    float4 aa = *(const float4*)(par + P_ATT1 + chb);
    float4 ab = *(const float4*)(par + P_ATT1 + chb + 4);
    a2[0].x = aa.x; a2[0].y = aa.y; a2[1].x = aa.z; a2[1].y = aa.w;
    a2[2].x = ab.x; a2[2].y = ab.y; a2[3].x = ab.z; a2[3].y = ab.w;
  }

  const int e0 = offs[dst], e1 = offs[dst + 1];
  const f2 zf2 = {0.f, 0.f};
  f2 acc2[4];
#pragma unroll
  for (int j = 0; j < 4; j++) acc2[j] = zf2;
  float denom = 0.f;

  const uint2 zq = {0, 0};
  int e = e0 + g;
  bool valid = e < e1;
  uint2 q = valid ? *(const uint2*)(xl1 + (size_t)csr[e] * F1 + chb) : zq;

  for (int base = e0; base < e1; base += 2) {
    const uint2 qc = q;
    const bool vc = valid;
    e += 2;
    valid = e < e1;
    q = valid ? *(const uint2*)(xl1 + (size_t)csr[e] * F1 + chb) : zq;

    f2 v2[4];
    unpack8fp8(qc, v2);
    f2 lt2 = zf2;
#pragma unroll
    for (int j = 0; j < 4; j++)
      lt2 = lrelu2(v2[j] + r2[j]) * a2[j] + lt2;
    float lt = vc ? (lt2.x + lt2.y) : -1e30f;
    lt += __shfl_xor(lt, 1, 64);
    lt += __shfl_xor(lt, 2, 64);
    lt += __shfl_xor(lt, 4, 64);
    float p = __expf(fminf(lt, 60.f));
    denom += p;
    f2 pv; pv.x = p; pv.y = p;
#pragma unroll
    for (int j = 0; j < 4; j++) acc2[j] = pv * v2[j] + acc2[j];
  }

  denom += __shfl_xor(denom, 32, 64);
#pragma unroll
  for (int j = 0; j < 4; j++) {
    acc2[j].x += __shfl_xor(acc2[j].x, 32, 64);
    acc2[j].y += __shfl_xor(acc2[j].y, 32, 64);
  }

  if (g == 0) {
    float inv = 1.f / (denom + EPS_A);
    __align__(16) bf16 ob[8];
#pragma unroll
    for (int j = 0; j < 4; j++) {
      float o0 = fmaxf(acc2[j].x * inv + par[P_BIAS1 + chb + 2*j],     0.f);
      float o1 = fmaxf(acc2[j].y * inv + par[P_BIAS1 + chb + 2*j + 1], 0.f);
      ob[2*j] = (bf16)o0; ob[2*j+1] = (bf16)o1;
    }
    *(uint4*)(hout + (size_t)dst * F1 + chb) = *(uint4*)ob;
  }
}

// ---------------- layer-2 aggregation (R14 shape) ----------------
__global__ __launch_bounds__(256, 4) void agg2_k(
    const fp8_t* __restrict__ xl2, const bf16* __restrict__ xr2,
    const float* __restrict__ par,
    const int* __restrict__ offs, const int* __restrict__ csr,
    bf16* __restrict__ h2) {
  const int dst = blockIdx.x * 4 + (threadIdx.x >> 6);
  if (dst >= N_NODES) return;
  const int lane = threadIdx.x & 63;
  const int g = lane >> 4;
  const int sl = lane & 15;
  const int chb = sl * 8;

  f2 r2[4], a2[4];
  load8bf2(xr2 + (size_t)dst * F2 + chb, r2);
  {
    float4 aa = *(const float4*)(par + P_ATT2 + chb);
    float4 ab = *(const float4*)(par + P_ATT2 + chb + 4);
    a2[0].x = aa.x; a2[0].y = aa.y; a2[1].x = aa.z; a2[1].y = aa.w;
    a2[2].x = ab.x; a2[2].y = ab.y; a2[3].x = ab.z; a2[3].y = ab.w;
  }

  const int e0 = offs[dst], e1 = offs[dst + 1];
  const f2 zf2 = {0.f, 0.f};
  f2 acc2[4];
#pragma unroll
  for (int j = 0; j < 4; j++) acc2[j] = zf2;
  float denom = 0.f;

  const uint2 zq = {0, 0};
  int e = e0 + g;
  bool valid = e < e1;
  uint2 q = valid ? *(const uint2*)(xl2 + (size_t)csr[e] * F2 + chb) : zq;

  for (int base = e0; base < e1; base += 4) {
    const uint2 qc = q;
    const bool vc = valid;
    e += 4;
    valid = e < e1;
    q = valid ? *(const uint2*)(xl2 + (size_t)csr[e] * F2 + chb) : zq;

    f2 v2[4];
    unpack8fp8(qc, v2);
    f2 lt2 = zf2;
#pragma unroll
    for (int j = 0; j < 4; j++)
      lt2 = lrelu2(v2[j] + r2[j]) * a2[j] + lt2;
    float lt = vc ? (lt2.x + lt2.y) : -1e30f;
    lt += __shfl_xor(lt, 1, 64);
    lt += __shfl_xor(lt, 2, 64);
    lt += __shfl_xor(lt, 4, 64);
    lt += __shfl_xor(lt, 8, 64);
    float p = __expf(fminf(lt, 60.f));
    denom += p;
    f2 pv; pv.x = p; pv.y = p;
#pragma unroll
    for (int j = 0; j < 4; j++) acc2[j] = pv * v2[j] + acc2[j];
  }

#pragma unroll
  for (int m = 16; m <= 32; m <<= 1) {
    denom += __shfl_xor(denom, m, 64);
#pragma unroll
    for (int j = 0; j < 4; j++) {
      acc2[j].x += __shfl_xor(acc2[j].x, m, 64);
      acc2[j].y += __shfl_xor(acc2[j].y, m, 64);
    }
  }

  if (g == 0) {
    float inv = 1.f / (denom + EPS_A);
    __align__(16) bf16 ob[8];
#pragma unroll
    for (int j = 0; j < 4; j++) {
      float o0 = fmaxf(acc2[j].x * inv + par[P_BIAS2 + chb + 2*j],     0.f);
      float o1 = fmaxf(acc2[j].y * inv + par[P_BIAS2 + chb + 2*j + 1], 0.f);
      ob[2*j] = (bf16)o0; ob[2*j+1] = (bf16)o1;
    }
    *(uint4*)(h2 + (size_t)dst * F2 + chb) = *(uint4*)ob;
  }
}

// ---------------- pooling: 8 slices/graph + tiny finalize (R17 form) ----------------
__global__ __launch_bounds__(256) void poolp_k(
    const bf16* __restrict__ h2, const int* __restrict__ gs,
    const int* __restrict__ ge, float* __restrict__ psum) {
  const int g = blockIdx.x >> 3, slice = blockIdx.x & 7;
  const int t = threadIdx.x;
  const int c = t & 127, half = t >> 7;
  int s = gs[g] - 1, eex = ge[g];        // +1 encoding; 0 = unset
  if (s < 0 || eex <= s) return;
  float sum = 0.f;
  for (int n = s + slice * 2 + half; n < eex; n += 16)
    sum += (float)h2[(size_t)n * F2 + c];
  atomicAdd(&psum[g * F2 + c], sum);
}

__global__ void poolf_k(const float* __restrict__ psum,
                        const int* __restrict__ gs, const int* __restrict__ ge,
                        const void* __restrict__ x, void* __restrict__ out) {
  int i = blockIdx.x * 256 + threadIdx.x;
  if (i >= NGRAPH * F2) return;
  const int flag = detect_f32_wave(x);
  int g = i >> 7;
  int s = gs[g] - 1, eex = ge[g];
  float cnt = (s >= 0 && eex > s) ? (float)(eex - s) : 1.f;
  float v = psum[i] / cnt;
  if (flag) ((float*)out)[i] = v;
  else      ((bf16*)out)[i] = (bf16)v;
}

// ---------------- launch ----------------
extern "C" void kernel_launch(void* const* d_in, const int* in_sizes, int n_in,
                              void* d_out, int out_size, void* d_ws, size_t ws_size,
                              hipStream_t stream) {
  (void)in_sizes; (void)n_in; (void)out_size; (void)ws_size;
  const void* x     = d_in[0];
  const int*  ei    = (const int*)d_in[1];
  const int*  batch = (const int*)d_in[2];

  char* ws = (char*)d_ws;
  float* par  = (float*)(ws + OFF_PAR);
  fp8_t* xl1 = (fp8_t*)(ws + OFF_XL1);
  bf16* xr1 = (bf16*)(ws + OFF_XR1);
  bf16* h   = (bf16*)(ws + OFF_H);
  fp8_t* xl2 = (fp8_t*)(ws + OFF_XL2);
  bf16* xr2 = (bf16*)(ws + OFF_XR2);
  bf16* h2  = (bf16*)(ws + OFF_H2);
  bf16* xb  = (bf16*)(ws + OFF_XB);
  bf16* wt1 = (bf16*)(ws + OFF_WT1);
  bf16* wt2 = (bf16*)(ws + OFF_WT2);
  int* cnt    = (int*)(ws + OFF_CNT);
  int* offs   = (int*)(ws + OFF_OFFS);
  int* offs_p = (int*)(ws + OFF_OFFSP);
  int* csr    = (int*)(ws + OFF_CSR);
  int* gs     = (int*)(ws + OFF_GS);
  int* ge     = (int*)(ws + OFF_GE);
  int* bsum   = (int*)(ws + OFF_BS);
  float* psum = (float*)(ws + OFF_PSUM);
  int* rank   = (int*)(ws + OFF_RANK);

  // single zero-init: cnt | gs | ge | psum (contiguous)
  hipMemsetAsync(cnt, 0, OFF_ZEND - OFF_CNT, stream);

  PrepArgs pa;
  pa.x = x; pa.ei = ei; pa.batch = batch;
  for (int i = 0; i < 12; i++) pa.src[i] = d_in[3 + i];
  const int prep_blocks = B_CVT + B_XP + B_W1 + B_W2 + B_BND + B_CNT;
  prep_k<<<prep_blocks, 256, 0, stream>>>(pa, par, xb, wt1, wt2, gs, ge, cnt, rank);

  scan_a<<<SCAN_BLKS, 256, 0, stream>>>(cnt, offs_p, bsum);

  mega_k<<<MEGA_SCANC + GBLK + SBL, 256, 0, stream>>>(
      xb, wt1, par, xl1, xr1, ei, offs_p, bsum, rank, offs, csr);

  agg1_k<<<(N_NODES + 3) / 4, 256, 0, stream>>>(xl1, xr1, par, offs, csr, h);
  gemm2_mfma_k<<<GBLK, 256, 0, stream>>>(h, wt2, par, xl2, xr2);
  agg2_k<<<(N_NODES + 3) / 4, 256, 0, stream>>>(xl2, xr2, par, offs, csr, h2);
  poolp_k<<<NGRAPH * 8, 256, 0, stream>>>(h2, gs, ge, psum);
  poolf_k<<<(NGRAPH * F2 + 255) / 256, 256, 0, stream>>>(psum, gs, ge, x, d_out);
}